// Round 6
// baseline (1934.698 us; speedup 1.0000x reference)
//
#include <hip/hip_runtime.h>
#include <hip/hip_fp16.h>

typedef _Float16 half8 __attribute__((ext_vector_type(8)));
typedef float floatx4 __attribute__((ext_vector_type(4)));
typedef unsigned long long u64;

// workspace layout
#define HBUF_BYTES (2ull * 16 * 1024 * 8)   // [parity][group][dim] u64 (4 f16 batches) = 256 KB
#define CTL_BYTES  (32ull * 1024)           // reserved
#define XP_OFF     (HBUF_BYTES + CTL_BYTES)
#define XP_BYTES   (512ull * 64 * 1024 * 2) // x_proj f16 [t][b][dim] = 64 MB

#define TAG_BIT    (1ull << 14)             // bit14 of h[0]: always 0 for tanh outputs

union pack4 { unsigned long long u; _Float16 h[4]; };

__device__ inline half8 cvt8(const float4 a, const float4 b) {
    half8 r;
    r[0] = (_Float16)a.x; r[1] = (_Float16)a.y; r[2] = (_Float16)a.z; r[3] = (_Float16)a.w;
    r[4] = (_Float16)b.x; r[5] = (_Float16)b.y; r[6] = (_Float16)b.z; r[7] = (_Float16)b.w;
    return r;
}

// ---------------------------------------------------------------------------
// Phase A: x_proj = emb[src] @ W_xh^T + b_xh.
// (register-prefetch pipeline, unchanged — single-variable discipline)
// ---------------------------------------------------------------------------
__global__ __launch_bounds__(256) void xproj_kernel(
    const int* __restrict__ src, const float* __restrict__ emb,
    const float* __restrict__ Wxh, const float* __restrict__ bxh,
    _Float16* __restrict__ xp)
{
    __shared__ _Float16 As[128][40];
    __shared__ _Float16 Bs[128][40];

    const int tid  = threadIdx.x;
    const int lane = tid & 63;
    const int w    = tid >> 6;
    const int m15  = lane & 15;
    const int quad = lane >> 4;
    const int bid  = blockIdx.x;
    const int bn   = bid & 7;
    const int bm   = bid >> 3;
    const int m0   = bm * 128, n0 = bn * 128;
    const int wm   = w & 1, wn = w >> 1;

    const int  srow = tid >> 1;
    const int  scol = (tid & 1) * 16;
    const long arow = (long)src[m0 + srow] * 1024;
    const float* abase = emb + arow + scol;
    const float* bbase = Wxh + (long)(n0 + srow) * 1024 + scol;

    floatx4 zero4 = {0.f, 0.f, 0.f, 0.f};
    floatx4 acc[4][4];
#pragma unroll
    for (int mt = 0; mt < 4; mt++)
#pragma unroll
        for (int nt = 0; nt < 4; nt++) acc[mt][nt] = zero4;

    // preload k-chunk 0 into registers
    float4 a0 = *(const float4*)(abase);
    float4 a1 = *(const float4*)(abase + 4);
    float4 a2 = *(const float4*)(abase + 8);
    float4 a3 = *(const float4*)(abase + 12);
    float4 b0 = *(const float4*)(bbase);
    float4 b1 = *(const float4*)(bbase + 4);
    float4 b2 = *(const float4*)(bbase + 8);
    float4 b3 = *(const float4*)(bbase + 12);

    for (int k0 = 0; k0 < 1024; k0 += 32) {
        *(half8*)&As[srow][scol]     = cvt8(a0, a1);
        *(half8*)&As[srow][scol + 8] = cvt8(a2, a3);
        *(half8*)&Bs[srow][scol]     = cvt8(b0, b1);
        *(half8*)&Bs[srow][scol + 8] = cvt8(b2, b3);
        __syncthreads();

        if (k0 + 32 < 1024) {
            const int kn = k0 + 32;
            a0 = *(const float4*)(abase + kn);
            a1 = *(const float4*)(abase + kn + 4);
            a2 = *(const float4*)(abase + kn + 8);
            a3 = *(const float4*)(abase + kn + 12);
            b0 = *(const float4*)(bbase + kn);
            b1 = *(const float4*)(bbase + kn + 4);
            b2 = *(const float4*)(bbase + kn + 8);
            b3 = *(const float4*)(bbase + kn + 12);
        }

        half8 af[4], bf[4];
#pragma unroll
        for (int mt = 0; mt < 4; mt++)
            af[mt] = *(const half8*)&As[wm * 64 + mt * 16 + m15][quad * 8];
#pragma unroll
        for (int nt = 0; nt < 4; nt++)
            bf[nt] = *(const half8*)&Bs[wn * 64 + nt * 16 + m15][quad * 8];
#pragma unroll
        for (int mt = 0; mt < 4; mt++)
#pragma unroll
            for (int nt = 0; nt < 4; nt++)
                acc[mt][nt] = __builtin_amdgcn_mfma_f32_16x16x32_f16(
                    af[mt], bf[nt], acc[mt][nt], 0, 0, 0);

        __syncthreads();
    }

#pragma unroll
    for (int nt = 0; nt < 4; nt++) {
        const int n = n0 + wn * 64 + nt * 16 + m15;
        const float bias = bxh[n];
#pragma unroll
        for (int mt = 0; mt < 4; mt++) {
            const int mrow = m0 + wm * 64 + mt * 16 + quad * 4;
#pragma unroll
            for (int r = 0; r < 4; r++) {
                const int m = mrow + r;
                const int b = m >> 9;
                const int t = m & 511;
                xp[((long)t * 64 + b) * 1024 + n] = (_Float16)(acc[mt][nt][r] + bias);
            }
        }
    }
}

// ---------------------------------------------------------------------------
// Phase B: persistent recurrence, R10: ONE-WAVE WORKGROUPS.
// 1024 WGs x 64 threads: WG = (group g, n-tile of 16 dims), FULL K=1024.
// W slice = 16x1024 f16 = 128 VGPRs (same budget as the 4-wave split).
// Per step, each wave independently:
//   poll (16 coalesced u64 loads/lane, okmask partial re-issue, full MLP)
//   -> transpose into a PRIVATE 8.4KB hstage (no sharing, no barrier)
//   -> 32 MFMAs, 4 interleaved accumulator chains
//   -> tanh -> one 8B store per quad0 lane (coalesced 128B).
// ZERO barriers, zero cross-wave reduction, zero straggler coupling: each
// wave publishes the instant its own chain finishes. This removes the cred
// LDS round-trip + barrier + max-of-4-waves detection coupling of R8, and
// avoids R6's failure mode (LDS reads/CU/step unchanged at 4x8KB: each
// wave reads only its private tile).
// A-fragment rows >=4 are garbage-tolerant (C[r][*] depends only on A[r][*]
// and we consume C rows 0..3 only), so: no zero rows, no hstage init, lanes
// m15>=4 broadcast-read row m15&3. Row stride 1056 f16 keeps the b128
// fragment reads at worst 2-way (free) bank aliasing.
// Sync medium unchanged (R4-proven): packed [parity][group][dim] u64 words,
// tag(h_s) = ((s+1)>>1)&1 in bit14 of h[0]; memset zeros: h_0 slot never
// polled (t=0 skips poll+MFMA since h_0=0 exactly), h_1 slot reads stale.
// Back-pressure: wave stores h_{t+1} (overwriting h_{t-1}) only after
// validating ALL of h_t; a validated h_t word from producer Q implies Q's
// h_{t-1} poll loads all completed (program order). 8B word atomicity
// handles partial arrival; no fences anywhere.
// ---------------------------------------------------------------------------
__global__ __launch_bounds__(64, 1) void rnn_kernel(
    const float* __restrict__ Whh, const _Float16* __restrict__ xp,
    unsigned long long* __restrict__ hb, float* __restrict__ out)
{
    __shared__ _Float16 hstage[4][1056];    // private per 1-wave WG

    const int lane = threadIdx.x;           // 0..63
    const int m15  = lane & 15;
    const int quad = lane >> 4;
    const int wg   = blockIdx.x;            // 0..1023
    const int g    = wg >> 6;               // group 0..15
    const int n0   = (wg & 63) * 16;        // this wave's 16 output dims
    const int b0   = g * 4;

    // W_hh rows n0..n0+15, full K -> 32 x half8 = 128 VGPRs
    half8 Wf[32];
    {
        const float* wrow = Whh + (long)(n0 + m15) * 1024 + quad * 8;
#pragma unroll
        for (int kk = 0; kk < 32; kk++) {
            float4 lo = *(const float4*)(wrow + kk * 32);
            float4 hi = *(const float4*)(wrow + kk * 32 + 4);
            Wf[kk] = cvt8(lo, hi);
        }
    }

    const int dim = n0 + m15;               // quad0 epilogue dim
    float xv[4] = {0.f, 0.f, 0.f, 0.f};
    if (quad == 0) {
#pragma unroll
        for (int r = 0; r < 4; r++)
            xv[r] = (float)xp[((long)0 * 64 + b0 + r) * 1024 + dim];
    }

    floatx4 zero4 = {0.f, 0.f, 0.f, 0.f};

    for (int t = 0; t < 512; t++) {
        floatx4 acc[4] = {zero4, zero4, zero4, zero4};

        if (t > 0) {
            // (A) batched poll of the group's FULL h_t: 16 coalesced u64
            // loads per lane (512B/instr across the wave), okmask re-issues
            // only stale words. All 16 detections proceed concurrently.
            const u64* hcu = hb + (size_t)(t & 1) * 16384 + (size_t)g * 1024;
            const u64 exp_tag = (u64)(((t + 1) >> 1) & 1) << 14;

            u64 v[16];
            unsigned done = 0;
            do {
#pragma unroll
                for (int i = 0; i < 16; i++)
                    if (!(done & (1u << i)))
                        v[i] = __hip_atomic_load(hcu + lane + 64 * i,
                                                 __ATOMIC_RELAXED,
                                                 __HIP_MEMORY_SCOPE_AGENT);
#pragma unroll
                for (int i = 0; i < 16; i++)
                    if (!(done & (1u << i)) && ((v[i] & TAG_BIT) == exp_tag))
                        done |= (1u << i);
            } while (done != 0xFFFFu);

            // (B) transpose into private hstage (2-way-free b16 writes)
#pragma unroll
            for (int i = 0; i < 16; i++) {
                pack4 p; p.u = v[i] & ~TAG_BIT;
                const int d = lane + 64 * i;
#pragma unroll
                for (int b = 0; b < 4; b++) hstage[b][d] = p.h[b];
            }

            // (C) full-K GEMM for this wave's 16 dims: 32 MFMAs, 4 chains.
            // Rows m15>=4 broadcast-read row m15&3 (garbage-tolerant).
#pragma unroll
            for (int kk = 0; kk < 32; kk++) {
                half8 a = *(const half8*)&hstage[m15 & 3][kk * 32 + quad * 8];
                acc[kk & 3] = __builtin_amdgcn_mfma_f32_16x16x32_f16(
                    a, Wf[kk], acc[kk & 3], 0, 0, 0);
            }
        }
        floatx4 dsum = (acc[0] + acc[1]) + (acc[2] + acc[3]);

        // (D) epilogue: quad0 lane m15 holds batches 0..3 of dim n0+m15.
        // tanh, tag, ONE 8B relaxed agent-atomic store = the publication.
        if (quad == 0) {
            pack4 p;
#pragma unroll
            for (int r = 0; r < 4; r++) {
                float pre  = dsum[r] + xv[r];
                float e    = __expf(2.0f * pre);
                float hval = 1.0f - 2.0f / (e + 1.0f);   // tanh
                p.h[r] = (_Float16)hval;
                if (t == 511) out[(b0 + r) * 1024 + dim] = hval;
            }
            if (t < 511) {
                unsigned long long* hnu =
                    hb + (size_t)((t + 1) & 1) * 16384 + (size_t)g * 1024;
                const u64 st_tag = (u64)(((t + 2) >> 1) & 1) << 14;
                __hip_atomic_store(hnu + dim, p.u | st_tag, __ATOMIC_RELAXED,
                                   __HIP_MEMORY_SCOPE_AGENT);
            }
        }

        // (E) x_proj prefetch for t+1; drains while the next poll spins
        if (t < 511 && quad == 0) {
#pragma unroll
            for (int r = 0; r < 4; r++)
                xv[r] = (float)xp[((long)(t + 1) * 64 + b0 + r) * 1024 + dim];
        }
    }
}

extern "C" void kernel_launch(void* const* d_in, const int* in_sizes, int n_in,
                              void* d_out, int out_size, void* d_ws, size_t ws_size,
                              hipStream_t stream) {
    const int*   src = (const int*)d_in[0];
    const float* emb = (const float*)d_in[1];
    const float* Wxh = (const float*)d_in[2];
    const float* bxh = (const float*)d_in[3];
    const float* Whh = (const float*)d_in[4];
    float* out = (float*)d_out;

    char* ws = (char*)d_ws;
    unsigned long long* hb = (unsigned long long*)ws;
    _Float16* xp = (_Float16*)(ws + XP_OFF);

    // zero h buffers: h_0 slot is never polled (t=0 skips poll); h_1 slot
    // zeros read as stale (tag 0 != 1) so consumers block until real h_1.
    hipMemsetAsync(ws, 0, HBUF_BYTES, stream);

    hipLaunchKernelGGL(xproj_kernel, dim3(2048), dim3(256), 0, stream,
                       src, emb, Wxh, bxh, xp);

    hipLaunchKernelGGL(rnn_kernel, dim3(1024), dim3(64), 0, stream,
                       Whh, xp, hb, out);
}